// Round 9
// baseline (536.237 us; speedup 1.0000x reference)
//
#include <hip/hip_runtime.h>
#include <hip/hip_bf16.h>
#include <cstdint>

typedef uint16_t u16;
typedef __attribute__((ext_vector_type(8))) short short8;
typedef __attribute__((ext_vector_type(4))) float floatx4;

#define S_LEN 512
#define N_TOT 3584              // 7*512
#define HG_ROW 8388608          // 512*32*512 : flat base of row S in (S+1,B,H)
#define CT_BASE 8404992         // 513*32*512 : c_t base in out (f32 elements)

__device__ __forceinline__ float b2f(u16 u) {
  union { uint32_t i; float f; } v; v.i = ((uint32_t)u) << 16; return v.f;
}
__device__ __forceinline__ uint32_t pk2(float a, float b) {
  __hip_bfloat162 t = __float22bfloat162_rn(float2{a, b});
  return *(uint32_t*)&t;
}
__device__ __forceinline__ u16 f2b(float a) { return (u16)pk2(a, 0.f); }  // bf16 RN
__device__ __forceinline__ uint4 pack8f(const float* p) {
  const float4 x = *(const float4*)p;
  const float4 y = *(const float4*)(p + 4);
  uint4 r;
  r.x = pk2(x.x, x.y); r.y = pk2(x.z, x.w);
  r.z = pk2(y.x, y.y); r.w = pk2(y.z, y.w);
  return r;
}
__device__ __forceinline__ float sigm(float x) { return 1.f / (1.f + __expf(-x)); }
__device__ __forceinline__ float tanh_(float x) { return 2.f / (1.f + __expf(-2.f * x)) - 1.f; }
__device__ __forceinline__ int sl_stride(const int* p) { return (p[1] == 0) ? 2 : 1; }

__device__ __forceinline__ void gl_lds16(const void* g, void* l) {
  __builtin_amdgcn_global_load_lds((const __attribute__((address_space(1))) uint32_t*)g,
                                   (__attribute__((address_space(3))) uint32_t*)l, 16, 0, 0);
}

// ============ fused prep: hpad | seqs->bf16 | Bcat | Bfi | zero3 | rowmap0 | masked-out0 ====
// region-dispatched by blockIdx.x; saves 4 kernel launches vs separate kernels.
__global__ void k_prep(const float* __restrict__ h0, const int* __restrict__ seq_lens,
                       const float* __restrict__ seqs, const float* __restrict__ Ww,
                       const float* __restrict__ Wu, const float* __restrict__ Su,
                       u16* __restrict__ hpad, u16* __restrict__ seqsb,
                       u16* __restrict__ Bcat, u16* __restrict__ Bfi,
                       float* __restrict__ zero3, int* __restrict__ rowmap,
                       float* __restrict__ out) {
  int blk = blockIdx.x;
  const int tid = threadIdx.x;
  if (blk < 4112) {                              // hpad = [32 zero | masked bf16 | 32 zero]
    int i = blk * 256 + tid;
    int row = i >> 6, cb = (i & 63) * 8;
    uint4 v = make_uint4(0u, 0u, 0u, 0u);
    if (row >= 32 && row < 16416) {
      int m = row - 32;
      if ((m >> 5) < seq_lens[(m & 31) * sl_stride(seq_lens)])
        v = pack8f(h0 + (size_t)m * 512 + cb);
    }
    *(uint4*)(hpad + (size_t)row * 512 + cb) = v;
    return;
  }
  blk -= 4112;
  if (blk < 4096) {                              // seqs f32 -> bf16
    size_t o = ((size_t)blk * 256 + tid) * 8;
    *(uint4*)(seqsb + o) = pack8f(seqs + o);
    return;
  }
  blk -= 4096;
  if (blk < 3584) {                              // Bcat[n] = [Ww row | Wu row] bf16
    int i = blk * 256 + tid;
    int n = i >> 8, col = (i & 255) * 8;
    const float* src = (col < 1536) ? Ww + (size_t)n * 1536 + col
                                    : Wu + (size_t)n * 512 + (col - 1536);
    *(uint4*)(Bcat + (size_t)n * 2048 + col) = pack8f(src);
    return;
  }
  blk -= 3584;
  if (blk < 128) {                               // Bfi = bf16(Su[1])
    size_t o = ((size_t)blk * 256 + tid) * 8;
    *(uint4*)(Bfi + o) = pack8f(Su + 262144 + o);
    return;
  }
  blk -= 128;
  if (blk < 192) {                               // zero denom+cacc+hhat (49152 f32)
    int i = blk * 256 + tid;
    if (i < 49152) zero3[i] = 0.f;
    return;
  }
  blk -= 192;
  if (blk < 65) {                                // zero rowmap (16640 ints)
    rowmap[blk * 256 + tid] = 0;
    return;
  }
  blk -= 65;
  {                                              // zero masked out rows (h_w and c_w parts)
    int i = blk * 256 + tid;                     // 4096 blocks -> 16384*64
    int m = i >> 6, grp = (i & 63) * 8;
    int s = m >> 5, b = m & 31;
    if (s >= seq_lens[b * sl_stride(seq_lens)]) {
      float4 z = {0.f, 0.f, 0.f, 0.f};
      float* p = out + (size_t)m * 512 + grp;
      *(float4*)p = z; *(float4*)(p + 4) = z;
      float* pq = p + (size_t)CT_BASE;
      *(float4*)pq = z; *(float4*)(pq + 4) = z;
    }
  }
}

// ---- rowmap: meta[0]=live=sum(len); meta[1+b]=exclusive prefix; map lists live rows b-major ----
__global__ void k_map0(const int* __restrict__ seq_lens, int* __restrict__ meta) {
  int lane = threadIdx.x;                        // 64 threads, 1 wave
  int len = (lane < 32) ? seq_lens[lane * sl_stride(seq_lens)] : 0;
  int x = len;
#pragma unroll
  for (int d = 1; d < 32; d <<= 1) {
    int y = __shfl_up(x, d);
    if (lane >= d) x += y;
  }
  if (lane < 32) meta[1 + lane] = x - len;       // exclusive prefix for b
  if (lane == 31) meta[0] = x;                   // live count
}

__global__ void k_mapfill(const int* __restrict__ seq_lens, const int* __restrict__ meta,
                          int* __restrict__ rowmap) {
  int i = blockIdx.x * 256 + threadIdx.x;        // 64 blocks -> 16384 = s*32+b
  int b = i & 31, s = i >> 5;
  if (s < seq_lens[b * sl_stride(seq_lens)])
    rowmap[meta[1 + b] + s] = i;
}

// ---- h_hat accumulation: parallel over s, atomics (hpad already masked) ----
__global__ void k_hhat(const u16* __restrict__ hpad, float* __restrict__ hhat) {
  int id = blockIdx.x * 256 + threadIdx.x;       // 16384 = b*512+h
  int b = id >> 9, h = id & 511;
  int s0 = blockIdx.y * 32;
  const u16* p = hpad + (size_t)(32 + s0 * 32 + b) * 512 + h;
  float s = 0.f;
#pragma unroll 4
  for (int i = 0; i < 32; ++i) s += b2f(p[(size_t)i * 16384]);
  atomicAdd(hhat + id, s * (1.f / 512.f));
}

// ---- small matmuls, wave-per-output, lane-split K=512, coalesced (proven form) ----
__global__ void k_small(const float* __restrict__ h0, const float* __restrict__ Sw,
                        const float* __restrict__ Su, const float* __restrict__ Sb,
                        const float* __restrict__ Wv, const float* __restrict__ Wb,
                        const float* __restrict__ hhat,
                        float* __restrict__ sg0, float* __restrict__ sg2,
                        float* __restrict__ a1v, float* __restrict__ Vb) {
  int o = blockIdx.x * 4 + (threadIdx.x >> 6);   // wave id = output id (163840)
  int lane = threadIdx.x & 63;
  int k0 = lane * 8;
  const float* hg1base = h0 + (size_t)HG_ROW;
  float acc = 0.f;
  float bias;
  float* dst;
  if (o < 49152) {
    int job = o >> 14, r = o & 16383;
    int b = r >> 9, hh = r & 511;
    int widx = (job == 0) ? 0 : (job == 1) ? 2 : 1;
    const float* ar = hg1base + (size_t)b * 512 + k0;
    const float* br = Sw + ((size_t)widx * 512 + hh) * 512 + k0;
    float4 a0 = *(const float4*)ar, a1 = *(const float4*)(ar + 4);
    float4 b0 = *(const float4*)br, b1 = *(const float4*)(br + 4);
    acc = a0.x*b0.x + a0.y*b0.y + a0.z*b0.z + a0.w*b0.w
        + a1.x*b1.x + a1.y*b1.y + a1.z*b1.z + a1.w*b1.w;
    if (job != 2) {
      const float* hr = hhat + (size_t)b * 512 + k0;
      const float* ur = Su + ((size_t)widx * 512 + hh) * 512 + k0;
      float4 h0v = *(const float4*)hr, h1v = *(const float4*)(hr + 4);
      float4 u0 = *(const float4*)ur, u1 = *(const float4*)(ur + 4);
      acc += h0v.x*u0.x + h0v.y*u0.y + h0v.z*u0.z + h0v.w*u0.w
           + h1v.x*u1.x + h1v.y*u1.y + h1v.z*u1.z + h1v.w*u1.w;
    }
    bias = Sb[widx * 512 + hh];
    dst = (job == 0) ? sg0 + r : (job == 1) ? sg2 + r : a1v + r;
  } else {
    int r = o - 49152;                           // 7*16384
    int g = r >> 14, r2 = r & 16383;
    int b = r2 >> 9, n = r2 & 511;
    const float* ar = hg1base + (size_t)b * 512 + k0;
    const float* br = Wv + ((size_t)g * 512 + n) * 512 + k0;
    float4 a0 = *(const float4*)ar, a1 = *(const float4*)(ar + 4);
    float4 b0 = *(const float4*)br, b1 = *(const float4*)(br + 4);
    acc = a0.x*b0.x + a0.y*b0.y + a0.z*b0.z + a0.w*b0.w
        + a1.x*b1.x + a1.y*b1.y + a1.z*b1.z + a1.w*b1.w;
    bias = Wb[g * 512 + n];
    dst = Vb + ((size_t)g * 32 + b) * 512 + n;
  }
#pragma unroll
  for (int off2 = 32; off2 > 0; off2 >>= 1) acc += __shfl_down(acc, off2);
  if (lane == 0) *dst = acc + bias;
}

// ---- m97-style bf16 GEMM: kept for the small fi GEMM only (f32 C output) ----
struct GemmSrc {
  const u16* a[4];   // bf16, row length 512
  const u16* b[4];   // bf16, row length bld[t]
  int bld[4];
  int bcol[4];
};

__global__ __launch_bounds__(256)
void gemm_kernel(GemmSrc ga, float* __restrict__ C, int ldc, int nblk, int m0base) {
  __shared__ __align__(16) u16 sA[128 * 32];
  __shared__ __align__(16) u16 sB[128 * 32];
  const int tid = threadIdx.x;
  const int wave = tid >> 6, lane = tid & 63;
  const int wr = wave >> 1, wc = wave & 1;
  const int lhi = lane >> 4, llo = lane & 15;
  const int m0 = blockIdx.y * 128;
  const int n0 = blockIdx.x * 128;

  const int c0i = tid, c1i = 256 + tid;          // 16B staging chunks
  const int ar0 = c0i >> 2, ac0 = (c0i & 3) * 8;
  const int ar1 = c1i >> 2, ac1 = (c1i & 3) * 8;
  u16* lA0 = sA + c0i * 8; u16* lA1 = sA + c1i * 8;
  u16* lB0 = sB + c0i * 8; u16* lB1 = sB + c1i * 8;

  floatx4 acc[4][4];
#pragma unroll
  for (int i = 0; i < 4; ++i)
#pragma unroll
    for (int j = 0; j < 4; ++j) acc[i][j] = floatx4{0.f, 0.f, 0.f, 0.f};

  for (int t = 0; t < nblk; ++t) {
    const int bld = ga.bld[t];
    const u16* ab = ga.a[t] + (size_t)(m0base + m0) * 512;
    const u16* bb = ga.b[t] + (size_t)n0 * bld + ga.bcol[t];
    const u16* pa0 = ab + (size_t)ar0 * 512 + ac0;
    const u16* pa1 = ab + (size_t)ar1 * 512 + ac1;
    const u16* pb0 = bb + (size_t)ar0 * bld + ac0;
    const u16* pb1 = bb + (size_t)ar1 * bld + ac1;
#pragma unroll 1
    for (int kk = 0; kk < 16; ++kk) {
      const int kl = kk * 32;
      __syncthreads();                           // prior iter's LDS reads done
      gl_lds16(pa0 + kl, lA0);
      gl_lds16(pa1 + kl, lA1);
      gl_lds16(pb0 + kl, lB0);
      gl_lds16(pb1 + kl, lB1);
      __syncthreads();                           // drain global_load_lds
      short8 af[4], bf[4];
#pragma unroll
      for (int i = 0; i < 4; ++i) {
        af[i] = *(const short8*)(sA + (wr * 64 + i * 16 + llo) * 32 + lhi * 8);
        bf[i] = *(const short8*)(sB + (wc * 64 + i * 16 + llo) * 32 + lhi * 8);
      }
#pragma unroll
      for (int i = 0; i < 4; ++i)
#pragma unroll
        for (int j = 0; j < 4; ++j)
          acc[i][j] = __builtin_amdgcn_mfma_f32_16x16x32_bf16(af[i], bf[j], acc[i][j], 0, 0, 0);
    }
  }

  const int rb = m0 + wr * 64 + lhi * 4;
  const int cb = n0 + wc * 64 + llo;
#pragma unroll
  for (int i = 0; i < 4; ++i)
#pragma unroll
    for (int j = 0; j < 4; ++j)
#pragma unroll
      for (int r = 0; r < 4; ++r)
        C[(size_t)(rb + i * 16 + r) * ldc + (cb + j * 16)] = acc[i][j][r];
}

// ========== 256x256 2-phase counted-vmcnt bf16 GEMM on COMPACTED live rows ==========
// bf16 C output (round-8). K-loop/schedule unchanged (round-5 verified ledger;
// SQ_LDS_BANK_CONFLICT = 0). ROUND-9: kernel unchanged; host now launches ONE
// grid over all worst-case row-tiles when workspace fits the full bf16 C
// (117 MB) — dead blocks exit on meta check, HW backfills freed CUs with live
// blocks (1 block/CU at 128 KiB LDS means per-launch time = max block time, so
// chunk launches waste whole rounds; single launch runs ceil(live_blocks/256)
// rounds instead of 3).

#define SWZ(b) ((b) ^ ((((b) >> 7) & 7) << 4))

#define STAGE_A(KT, H, DB) do {                                               \
    const int t_ = (KT) >> 3;                                                 \
    const u16* ab_ = (t_ == 3) ? seqsb : (hpad + ((size_t)t_ << 14));         \
    const int ko_ = ((KT) & 7) << 6;                                          \
    gl_lds16(ab_ + (size_t)((H) ? aR10 : aR00) + ko_,                         \
             sm + (DB) * 32768 + (H) * 8192 + tid * 8);                       \
    gl_lds16(ab_ + (size_t)((H) ? aR11 : aR01) + ko_,                         \
             sm + (DB) * 32768 + (H) * 8192 + 4096 + tid * 8);                \
  } while (0)

#define STAGE_B(KT, H, DB) do {                                               \
    gl_lds16(Bcat + (size_t)(n0 + (H) * 128 + lr0) * 2048 + (KT) * 64 + le0,  \
             sm + (DB) * 32768 + 16384 + (H) * 8192 + tid * 8);               \
    gl_lds16(Bcat + (size_t)(n0 + (H) * 128 + lr1) * 2048 + (KT) * 64 + le1,  \
             sm + (DB) * 32768 + 16384 + (H) * 8192 + 4096 + tid * 8);        \
  } while (0)

#define READ_A(DST, MB)                                                       \
  _Pragma("unroll") for (int fi = 0; fi < 4; ++fi)                            \
  _Pragma("unroll") for (int ks = 0; ks < 2; ++ks)                            \
      DST[fi][ks] = *(const short8*)(sm + curo + (MB) * 8192 + aoff[fi][ks])

#define READ_B(DST, NB)                                                       \
  _Pragma("unroll") for (int fj = 0; fj < 2; ++fj)                            \
  _Pragma("unroll") for (int ks = 0; ks < 2; ++ks)                            \
      DST[fj][ks] = *(const short8*)(sm + curo + 16384 + (NB) * 8192 + boff[fj][ks])

#define MFMA_CLUSTER(MB, NB, AF, BF)                                          \
  __builtin_amdgcn_s_setprio(1);                                              \
  _Pragma("unroll") for (int fi = 0; fi < 4; ++fi)                            \
  _Pragma("unroll") for (int fj = 0; fj < 2; ++fj)                            \
  _Pragma("unroll") for (int ks = 0; ks < 2; ++ks)                            \
      acc[MB][NB][fi][fj] = __builtin_amdgcn_mfma_f32_16x16x32_bf16(          \
          AF[fi][ks], BF[fj][ks], acc[MB][NB][fi][fj], 0, 0, 0);              \
  __builtin_amdgcn_s_setprio(0)

__global__ __launch_bounds__(512, 2)
void gemm8_kernel(const u16* __restrict__ hpad, const u16* __restrict__ seqsb,
                  const u16* __restrict__ Bcat, const int* __restrict__ rowmap,
                  const int* __restrict__ meta, u16* __restrict__ C,
                  int m0base, int nkt) {
  __shared__ __align__(16) u16 sm[65536];        // 128 KiB
  const int tid = threadIdx.x;
  const int wave = tid >> 6, lane = tid & 63;
  const int llo = lane & 15, lhi = lane >> 4;
  const int wr = wave >> 2, wc = wave & 3;

  // XCD-aware bijective block-id swizzle (m204 formula)
  const int nwg = gridDim.x * gridDim.y;
  const int lin = blockIdx.y * gridDim.x + blockIdx.x;
  const int xcd = lin & 7, idx = lin >> 3;
  const int q = nwg >> 3, r = nwg & 7;
  const int sid = (xcd < r ? xcd * (q + 1) : r * (q + 1) + (xcd - r) * q) + idx;
  const int m0 = (sid / 14) * 256;
  const int n0 = (sid % 14) * 256;

  const int live = meta[0];
  if (m0base + m0 >= live) return;               // dead tile (uniform) -> exit

  // staging source coords: linear LDS dest chunk i*16B holds logical byte SWZ(i*16)
  const int p0 = tid * 16, p1 = (512 + tid) * 16;
  const int q0 = SWZ(p0), q1 = SWZ(p1);
  const int lr0 = q0 >> 7, le0 = (q0 & 127) >> 1;
  const int lr1 = q1 >> 7, le1 = (q1 & 127) >> 1;

  // gather: per-thread original-row element offsets (fixed across the K-loop)
  const int aR00 = rowmap[m0base + m0 + lr0] * 512 + le0;
  const int aR01 = rowmap[m0base + m0 + lr1] * 512 + le1;
  const int aR10 = rowmap[m0base + m0 + 128 + lr0] * 512 + le0;
  const int aR11 = rowmap[m0base + m0 + 128 + lr1] * 512 + le1;

  // swizzled fragment read offsets (u16 units), half-relative
  int aoff[4][2], boff[2][2];
#pragma unroll
  for (int fi = 0; fi < 4; ++fi)
#pragma unroll
    for (int ks = 0; ks < 2; ++ks) {
      int by = (wr * 64 + fi * 16 + llo) * 128 + ks * 64 + lhi * 16;
      aoff[fi][ks] = SWZ(by) >> 1;
    }
#pragma unroll
  for (int fj = 0; fj < 2; ++fj)
#pragma unroll
    for (int ks = 0; ks < 2; ++ks) {
      int by = (wc * 32 + fj * 16 + llo) * 128 + ks * 64 + lhi * 16;
      boff[fj][ks] = SWZ(by) >> 1;
    }

  floatx4 acc[2][2][4][2];
#pragma unroll
  for (int mb = 0; mb < 2; ++mb)
#pragma unroll
    for (int nb = 0; nb < 2; ++nb)
#pragma unroll
      for (int fi = 0; fi < 4; ++fi)
#pragma unroll
        for (int fj = 0; fj < 2; ++fj)
          acc[mb][nb][fi][fj] = floatx4{0.f, 0.f, 0.f, 0.f};

  // prologue: kt0 fully + kt1.{A0,B0}; vmcnt(4) -> kt0 landed, 4 ops in flight
  STAGE_A(0, 0, 0); STAGE_B(0, 0, 0); STAGE_B(0, 1, 0); STAGE_A(0, 1, 0);
  STAGE_A(1, 0, 1); STAGE_B(1, 0, 1);
  asm volatile("s_waitcnt vmcnt(4)" ::: "memory");
  __builtin_amdgcn_s_barrier();

  short8 af[4][2], b0f[2][2], b1f[2][2];
  for (int j = 0; j < nkt; ++j) {
    const int cur = j & 1, nxt = cur ^ 1;
    const int curo = cur * 32768;
    // ---------------- phase A ----------------
    READ_A(af, 0);
    READ_B(b0f, 0);
    __builtin_amdgcn_sched_barrier(0);           // pin: b1f's 4 reads issue last
    READ_B(b1f, 1);
    if (j + 1 < nkt) {                           // stage kt j+1 -> nxt
      STAGE_B(j + 1, 1, nxt);
      STAGE_A(j + 1, 1, nxt);
    }
    __builtin_amdgcn_s_barrier();
    asm volatile("s_waitcnt lgkmcnt(4)" ::: "memory");   // A0+B0 done (DS in-order)
    __builtin_amdgcn_sched_barrier(0);
    MFMA_CLUSTER(0, 0, af, b0f);
    asm volatile("s_waitcnt lgkmcnt(0)" ::: "memory");   // B1 done
    __builtin_amdgcn_sched_barrier(0);
    MFMA_CLUSTER(0, 1, af, b1f);
    __builtin_amdgcn_s_barrier();
    // ---------------- phase B ----------------
    READ_A(af, 1);
    if (j + 2 < nkt) {                           // stage kt j+2 -> cur
      STAGE_A(j + 2, 0, cur);
      STAGE_B(j + 2, 0, cur);
    }
    __builtin_amdgcn_s_barrier();
    asm volatile("s_waitcnt lgkmcnt(0)" ::: "memory");
    __builtin_amdgcn_sched_barrier(0);
    MFMA_CLUSTER(1, 0, af, b0f);
    MFMA_CLUSTER(1, 1, af, b1f);
    if (j < nkt - 2) asm volatile("s_waitcnt vmcnt(4)" ::: "memory");
    else             asm volatile("s_waitcnt vmcnt(0)" ::: "memory");
    __builtin_amdgcn_s_barrier();
  }

#pragma unroll
  for (int mb = 0; mb < 2; ++mb)
#pragma unroll
    for (int nb = 0; nb < 2; ++nb)
#pragma unroll
      for (int fi = 0; fi < 4; ++fi)
#pragma unroll
        for (int fj = 0; fj < 2; ++fj)
#pragma unroll
          for (int rr = 0; rr < 4; ++rr)
            C[(size_t)(m0 + mb * 128 + wr * 64 + fi * 16 + lhi * 4 + rr) * N_TOT
              + (n0 + nb * 128 + wc * 32 + fj * 16 + llo)] = f2b(acc[mb][nb][fi][fj][rr]);
}

// ---- fi softmax-weighted reduction over s (chunked partials + atomics) ----
__global__ void k_fireduce(const float* __restrict__ Cfi, const float* __restrict__ a1v,
                           const float* __restrict__ c0, const int* __restrict__ seq_lens,
                           float* __restrict__ denom, float* __restrict__ cacc,
                           int sbase, int send) {
  int id = blockIdx.x * 256 + threadIdx.x;       // b*512+h
  int b = id >> 9, h = id & 511;
  int len = seq_lens[b * sl_stride(seq_lens)];
  int lim = (send < len) ? send : len;
  int s0 = sbase + blockIdx.y * 64;
  if (s0 >= lim) return;
  int s1 = (s0 + 64 < lim) ? s0 + 64 : lim;
  float a = a1v[id];
  float d = 0.f, ca = 0.f;
  for (int s = s0; s < s1; ++s) {
    size_t m = (size_t)(s * 32 + b);
    size_t ml = (size_t)((s - sbase) * 32 + b);
    float e = __expf(sigm(Cfi[ml * 512 + h] + a));
    d += e;
    ca += e * c0[m * 512 + h];
  }
  atomicAdd(&denom[id], d);
  atomicAdd(&cacc[id], ca);
}

// ---- global cell: c_g, h_g → out row S ----
__global__ void k_global(const float* __restrict__ sg0, const float* __restrict__ sg2,
                         const float* __restrict__ c0, const float* __restrict__ denom,
                         const float* __restrict__ cacc, float* __restrict__ out) {
  int id = blockIdx.x * 256 + threadIdx.x;       // 16384
  float fg = sigm(sg0[id]);
  float og = sigm(sg2[id]);
  float cg1 = c0[(size_t)HG_ROW + id];
  float dn = denom[id];
  float cg = fg * cg1 + cacc[id] / (dn > 0.f ? dn : 1.f);
  float hg = og * tanh_(cg);
  out[(size_t)HG_ROW + id] = hg;
  out[(size_t)CT_BASE + HG_ROW + id] = cg;
}

// ---- window epilogue on compact rows: gates softmax-5, c_w, h_w; scatter via rowmap ----
// Cch is bf16; dead blocks (cml >= live) exit on the meta check.
__global__ void k_epilogue(const u16* __restrict__ Cch, const float* __restrict__ Vb,
                           const float* __restrict__ c0, const int* __restrict__ seq_lens,
                           const int* __restrict__ rowmap, const int* __restrict__ meta,
                           float* __restrict__ out, int mbase) {
  int idx = blockIdx.x * 256 + threadIdx.x;      // chunk-local (compact ml, h)
  int ml = idx >> 9, h = idx & 511;
  int cml = mbase + ml;
  if (cml >= meta[0]) return;                    // past live rows (block-uniform)
  int mg = rowmap[cml];
  int s = mg >> 5, b = mg & 31;
  int len = seq_lens[b * sl_stride(seq_lens)];
  float pre[7];
#pragma unroll
  for (int g = 0; g < 7; ++g)
    pre[g] = b2f(Cch[(size_t)ml * N_TOT + g * 512 + h]) + Vb[(size_t)(g * 32 + b) * 512 + h];
  float i_ = sigm(pre[0]);
  float l_ = sigm(pre[1]);
  float r_ = sigm(pre[2]);
  float f_ = sigm(pre[3]);
  float sg = sigm(pre[4]);
  float o_ = sigm(pre[5]);
  float u_ = tanh_(pre[6]);
  float el = __expf(l_), ef = __expf(f_), er = __expf(r_), es = __expf(sg), ei = __expf(i_);
  float inv = 1.f / (el + ef + er + es + ei);
  float cw = 0.f;
  if (s < len) {                                 // always true for live rows
    float cl = (s >= 1) ? c0[(size_t)(mg - 32) * 512 + h] : 0.f;
    float cc = c0[(size_t)mg * 512 + h];
    float cr = (s + 1 < S_LEN && s + 1 < len) ? c0[(size_t)(mg + 32) * 512 + h] : 0.f;
    float cg1 = c0[(size_t)HG_ROW + b * 512 + h];
    cw = (el * cl + ef * cc + er * cr + es * cg1 + ei * u_) * inv;
  }
  float hw = o_ * tanh_(cw);
  size_t oi = (size_t)mg * 512 + h;
  out[oi] = hw;
  out[(size_t)CT_BASE + oi] = cw;
}

extern "C" void kernel_launch(void* const* d_in, const int* in_sizes, int n_in,
                              void* d_out, int out_size, void* d_ws, size_t ws_size,
                              hipStream_t stream) {
  const float* seqs = (const float*)d_in[0];
  const int* seq_lens = (const int*)d_in[1];
  const float* h0 = (const float*)d_in[2];
  const float* c0 = (const float*)d_in[3];
  const float* Ww = (const float*)d_in[4];
  const float* Wu = (const float*)d_in[5];
  const float* Wv = (const float*)d_in[6];
  const float* Wb = (const float*)d_in[7];
  const float* Sw = (const float*)d_in[8];
  const float* Su = (const float*)d_in[9];
  const float* Sb = (const float*)d_in[10];
  float* out = (float*)d_out;

  // ---- workspace layout (fixed ~49.8 MB) + adaptive C region ----
  char* ws = (char*)d_ws;
  size_t off = 0;
  float* denom = (float*)(ws + off); off += 16384 * 4;   // zeroed together:
  float* cacc  = (float*)(ws + off); off += 16384 * 4;   // denom, cacc, hhat
  float* hhat  = (float*)(ws + off); off += 16384 * 4;
  float* sg0  = (float*)(ws + off); off += 16384 * 4;
  float* sg2  = (float*)(ws + off); off += 16384 * 4;
  float* a1v  = (float*)(ws + off); off += 16384 * 4;
  float* Vb   = (float*)(ws + off); off += (size_t)7 * 16384 * 4;
  u16* hpad  = (u16*)(ws + off); off += (size_t)16448 * 512 * 2;   // 16.84 MB
  u16* seqsb = (u16*)(ws + off); off += (size_t)16384 * 512 * 2;   // 16.78 MB
  u16* Bcat  = (u16*)(ws + off); off += (size_t)3584 * 2048 * 2;   // 14.68 MB
  u16* Bfi   = (u16*)(ws + off); off += (size_t)512 * 512 * 2;     //  0.52 MB
  int* meta   = (int*)(ws + off); off += 64 * 4;                   // live + prefix
  int* rowmap = (int*)(ws + off); off += 16640 * 4;                // live-row gather map
  float* Cfi  = (float*)(ws + off);              // fi GEMM C (f32), aliases Cb16
  u16* Cb16   = (u16*)(ws + off);                // main GEMM C (bf16), sequential use

  size_t avail = (ws_size > off) ? (ws_size - off) : 0;

  // fused prep: hpad | seqs | Bcat | Bfi | zero3 | rowmap0 | masked-out zero
  k_prep<<<16273, 256, 0, stream>>>(h0, seq_lens, seqs, Ww, Wu, Su,
                                    hpad, seqsb, Bcat, Bfi, denom, rowmap, out);
  k_map0<<<1, 64, 0, stream>>>(seq_lens, meta);
  k_mapfill<<<64, 256, 0, stream>>>(seq_lens, meta, rowmap);
  k_hhat<<<dim3(64, 16), 256, 0, stream>>>(hpad, hhat);
  k_small<<<40960, 256, 0, stream>>>(h0, Sw, Su, Sb, Wv, Wb, hhat, sg0, sg2, a1v, Vb);

  // fi GEMM (16384 x 512) = h_w1 @ Su[1]^T, chunked over rows (old 128^2 kernel, f32 C)
  int fi_rows = (int)(avail / ((size_t)512 * 4));
  fi_rows = (fi_rows / 128) * 128;
  if (fi_rows > 16384) fi_rows = 16384;
  if (fi_rows < 128) fi_rows = 128;
  GemmSrc gfi;
  gfi.a[0] = hpad + 32 * 512; gfi.b[0] = Bfi; gfi.bld[0] = 512; gfi.bcol[0] = 0;
  for (int fb = 0; fb < 16384; fb += fi_rows) {
    int rows = (fi_rows < 16384 - fb) ? fi_rows : (16384 - fb);
    gemm_kernel<<<dim3(4, rows / 128), 256, 0, stream>>>(gfi, Cfi, 512, 1, fb);
    int sbase = fb / 32, scnt = rows / 32;
    k_fireduce<<<dim3(64, (scnt + 63) / 64), 256, 0, stream>>>(
        Cfi, a1v, c0, seq_lens, denom, cacc, sbase, sbase + scnt);
  }
  k_global<<<64, 256, 0, stream>>>(sg0, sg2, c0, denom, cacc, out);

  // main GEMM on compacted live rows (bf16 C).
  // Single launch if full bf16 C fits (117 MB): dead blocks exit on-device and
  // the scheduler backfills CUs -> ~ceil(live_blocks/256) rounds instead of one
  // full round per chunk launch. Else: bf16-sized chunk loop (proven fallback).
  const size_t full_bytes = (size_t)16384 * N_TOT * 2;
  if (avail >= full_bytes) {
    gemm8_kernel<<<dim3(14, 64), 512, 0, stream>>>(
        hpad, seqsb, Bcat, rowmap, meta, Cb16, 0, 32);
    k_epilogue<<<32768, 256, 0, stream>>>(Cb16, Vb, c0, seq_lens, rowmap, meta, out, 0);
  } else {
    int chunk_rows = (int)(avail / ((size_t)N_TOT * 2));
    chunk_rows = (chunk_rows / 256) * 256;
    if (chunk_rows > 8192) chunk_rows = 8192;
    if (chunk_rows < 256) chunk_rows = 256;
    for (int mb = 0; mb < 16384; mb += chunk_rows) {
      int rows = (chunk_rows < 16384 - mb) ? chunk_rows : (16384 - mb);
      gemm8_kernel<<<dim3(14, rows / 256), 512, 0, stream>>>(
          hpad, seqsb, Bcat, rowmap, meta, Cb16, mb, 32);
      k_epilogue<<<rows * 2, 256, 0, stream>>>(Cb16, Vb, c0, seq_lens, rowmap, meta, out, mb);
    }
  }
}

// Round 10
// 427.506 us; speedup vs baseline: 1.2543x; 1.2543x over previous
//
#include <hip/hip_runtime.h>
#include <hip/hip_bf16.h>
#include <cstdint>

typedef uint16_t u16;
typedef __attribute__((ext_vector_type(8))) short short8;
typedef __attribute__((ext_vector_type(4))) float floatx4;

#define S_LEN 512
#define N_TOT 3584              // 7*512
#define HG_ROW 8388608          // 512*32*512 : flat base of row S in (S+1,B,H)
#define CT_BASE 8404992         // 513*32*512 : c_t base in out (f32 elements)

__device__ __forceinline__ float b2f(u16 u) {
  union { uint32_t i; float f; } v; v.i = ((uint32_t)u) << 16; return v.f;
}
__device__ __forceinline__ uint32_t pk2(float a, float b) {
  __hip_bfloat162 t = __float22bfloat162_rn(float2{a, b});
  return *(uint32_t*)&t;
}
__device__ __forceinline__ u16 f2b(float a) { return (u16)pk2(a, 0.f); }  // bf16 RN
__device__ __forceinline__ uint4 pack8f(const float* p) {
  const float4 x = *(const float4*)p;
  const float4 y = *(const float4*)(p + 4);
  uint4 r;
  r.x = pk2(x.x, x.y); r.y = pk2(x.z, x.w);
  r.z = pk2(y.x, y.y); r.w = pk2(y.z, y.w);
  return r;
}
__device__ __forceinline__ float sigm(float x) { return 1.f / (1.f + __expf(-x)); }
__device__ __forceinline__ float tanh_(float x) { return 2.f / (1.f + __expf(-2.f * x)) - 1.f; }
__device__ __forceinline__ int sl_stride(const int* p) { return (p[1] == 0) ? 2 : 1; }

__device__ __forceinline__ void gl_lds16(const void* g, void* l) {
  __builtin_amdgcn_global_load_lds((const __attribute__((address_space(1))) uint32_t*)g,
                                   (__attribute__((address_space(3))) uint32_t*)l, 16, 0, 0);
}

// ============ fused prep ============================================================
// regions: hpad | seqs->bf16 | Bcat | Bfi | zero3 | rowmap0 | masked-out0 |
//          Ball (small-GEMM B, 5120x1024 bf16) | Ahg (pad-128 bf16 h_g1) | Ahh zero
__global__ void k_prep(const float* __restrict__ h0, const int* __restrict__ seq_lens,
                       const float* __restrict__ seqs, const float* __restrict__ Ww,
                       const float* __restrict__ Wu, const float* __restrict__ Su,
                       const float* __restrict__ Sw, const float* __restrict__ Wv,
                       u16* __restrict__ hpad, u16* __restrict__ seqsb,
                       u16* __restrict__ Bcat, u16* __restrict__ Bfi,
                       float* __restrict__ zero3, int* __restrict__ rowmap,
                       u16* __restrict__ Ball, u16* __restrict__ Ahg,
                       u16* __restrict__ Ahh, float* __restrict__ out) {
  int blk = blockIdx.x;
  const int tid = threadIdx.x;
  if (blk < 4112) {                              // hpad = [32 zero | masked bf16 | 32 zero]
    int i = blk * 256 + tid;
    int row = i >> 6, cb = (i & 63) * 8;
    uint4 v = make_uint4(0u, 0u, 0u, 0u);
    if (row >= 32 && row < 16416) {
      int m = row - 32;
      if ((m >> 5) < seq_lens[(m & 31) * sl_stride(seq_lens)])
        v = pack8f(h0 + (size_t)m * 512 + cb);
    }
    *(uint4*)(hpad + (size_t)row * 512 + cb) = v;
    return;
  }
  blk -= 4112;
  if (blk < 4096) {                              // seqs f32 -> bf16
    size_t o = ((size_t)blk * 256 + tid) * 8;
    *(uint4*)(seqsb + o) = pack8f(seqs + o);
    return;
  }
  blk -= 4096;
  if (blk < 3584) {                              // Bcat[n] = [Ww row | Wu row] bf16
    int i = blk * 256 + tid;
    int n = i >> 8, col = (i & 255) * 8;
    const float* src = (col < 1536) ? Ww + (size_t)n * 1536 + col
                                    : Wu + (size_t)n * 512 + (col - 1536);
    *(uint4*)(Bcat + (size_t)n * 2048 + col) = pack8f(src);
    return;
  }
  blk -= 3584;
  if (blk < 128) {                               // Bfi = bf16(Su[1])
    size_t o = ((size_t)blk * 256 + tid) * 8;
    *(uint4*)(Bfi + o) = pack8f(Su + 262144 + o);
    return;
  }
  blk -= 128;
  if (blk < 192) {                               // zero denom+cacc+hhat (49152 f32)
    int i = blk * 256 + tid;
    if (i < 49152) zero3[i] = 0.f;
    return;
  }
  blk -= 192;
  if (blk < 65) {                                // zero rowmap (16640 ints)
    rowmap[blk * 256 + tid] = 0;
    return;
  }
  blk -= 65;
  if (blk < 4096) {                              // zero masked out rows (h_w and c_w)
    int i = blk * 256 + tid;                     // 16384*64
    int m = i >> 6, grp = (i & 63) * 8;
    int s = m >> 5, b = m & 31;
    if (s >= seq_lens[b * sl_stride(seq_lens)]) {
      float4 z = {0.f, 0.f, 0.f, 0.f};
      float* p = out + (size_t)m * 512 + grp;
      *(float4*)p = z; *(float4*)(p + 4) = z;
      float* pq = p + (size_t)CT_BASE;
      *(float4*)pq = z; *(float4*)(pq + 4) = z;
    }
    return;
  }
  blk -= 4096;
  if (blk < 2560) {                              // Ball[n][0:512]=W_j[hh], [512:1024]=Su or 0
    int i = blk * 256 + tid;                     // n = j*512+hh; j: 0->Sw0 1->Sw2 2->Sw1 3+->Wv
    int n = i >> 7, c8 = (i & 127) * 8;
    int j = n >> 9, hh = n & 511;
    uint4 v;
    if (c8 < 512) {
      const float* src = (j == 0) ? Sw + (size_t)hh * 512 + c8
                       : (j == 1) ? Sw + (size_t)(1024 + hh) * 512 + c8
                       : (j == 2) ? Sw + (size_t)(512 + hh) * 512 + c8
                                  : Wv + (size_t)((j - 3) * 512 + hh) * 512 + c8;
      v = pack8f(src);
    } else if (j < 2) {
      v = pack8f(Su + (size_t)((j == 0 ? 0 : 1024) + hh) * 512 + (c8 - 512));
    } else {
      v = make_uint4(0u, 0u, 0u, 0u);
    }
    *(uint4*)(Ball + (size_t)n * 1024 + c8) = v;
    return;
  }
  blk -= 2560;
  if (blk < 32) {                                // Ahg: rows 0-31 = bf16(h_g1), rest 0
    int i = blk * 256 + tid;
    int row = i >> 6, c8 = (i & 63) * 8;
    uint4 v = make_uint4(0u, 0u, 0u, 0u);
    if (row < 32) v = pack8f(h0 + (size_t)HG_ROW + (size_t)row * 512 + c8);
    *(uint4*)(Ahg + (size_t)row * 512 + c8) = v;
    return;
  }
  blk -= 32;
  {                                              // Ahh zero (rows 0-31 filled after k_hhat)
    int i = blk * 256 + tid;
    *(uint4*)(Ahh + (size_t)i * 8) = make_uint4(0u, 0u, 0u, 0u);
  }
}

// ---- rowmap: meta[0]=live=sum(len); meta[1+b]=exclusive prefix; map lists live rows b-major ----
__global__ void k_map0(const int* __restrict__ seq_lens, int* __restrict__ meta) {
  int lane = threadIdx.x;                        // 64 threads, 1 wave
  int len = (lane < 32) ? seq_lens[lane * sl_stride(seq_lens)] : 0;
  int x = len;
#pragma unroll
  for (int d = 1; d < 32; d <<= 1) {
    int y = __shfl_up(x, d);
    if (lane >= d) x += y;
  }
  if (lane < 32) meta[1 + lane] = x - len;       // exclusive prefix for b
  if (lane == 31) meta[0] = x;                   // live count
}

__global__ void k_mapfill(const int* __restrict__ seq_lens, const int* __restrict__ meta,
                          int* __restrict__ rowmap) {
  int i = blockIdx.x * 256 + threadIdx.x;        // 64 blocks -> 16384 = s*32+b
  int b = i & 31, s = i >> 5;
  if (s < seq_lens[b * sl_stride(seq_lens)])
    rowmap[meta[1 + b] + s] = i;
}

// ---- h_hat accumulation: parallel over s, atomics (hpad already masked) ----
__global__ void k_hhat(const u16* __restrict__ hpad, float* __restrict__ hhat) {
  int id = blockIdx.x * 256 + threadIdx.x;       // 16384 = b*512+h
  int b = id >> 9, h = id & 511;
  int s0 = blockIdx.y * 32;
  const u16* p = hpad + (size_t)(32 + s0 * 32 + b) * 512 + h;
  float s = 0.f;
#pragma unroll 4
  for (int i = 0; i < 32; ++i) s += b2f(p[(size_t)i * 16384]);
  atomicAdd(hhat + id, s * (1.f / 512.f));
}

// ---- hhat f32 -> Ahh bf16 rows 0-31 (flat layouts identical) ----
__global__ void k_cvthh(const float* __restrict__ hhat, u16* __restrict__ Ahh) {
  int i = blockIdx.x * 256 + threadIdx.x;        // 8 blocks -> 2048 threads x 8 elems
  *(uint4*)(Ahh + (size_t)i * 8) = pack8f(hhat + (size_t)i * 8);
}

// ---- scatter small-GEMM C (rows 0-31 valid, ldc=5120) + bias -> sg0/sg2/a1v/Vb ----
__global__ void k_scatter(const float* __restrict__ Csm, const float* __restrict__ Sb,
                          const float* __restrict__ Wb,
                          float* __restrict__ sg0, float* __restrict__ sg2,
                          float* __restrict__ a1v, float* __restrict__ Vb) {
  int id = blockIdx.x * 256 + threadIdx.x;       // 640 blocks -> 163840 = j*16384 + b*512 + h
  int j = id >> 14, r = id & 16383;
  int b = r >> 9, h = r & 511;
  float v = Csm[(size_t)b * 5120 + j * 512 + h];
  if (j == 0)      sg0[r] = v + Sb[h];           // widx 0
  else if (j == 1) sg2[r] = v + Sb[1024 + h];    // widx 2
  else if (j == 2) a1v[r] = v + Sb[512 + h];     // widx 1
  else Vb[(size_t)((j - 3) * 32 + b) * 512 + h] = v + Wb[(j - 3) * 512 + h];
}

// ---- m97-style bf16 GEMM: small GEMMs (f32 C output) ----
struct GemmSrc {
  const u16* a[4];   // bf16, row length 512
  const u16* b[4];   // bf16, row length bld[t]
  int bld[4];
  int bcol[4];
};

__global__ __launch_bounds__(256)
void gemm_kernel(GemmSrc ga, float* __restrict__ C, int ldc, int nblk, int m0base) {
  __shared__ __align__(16) u16 sA[128 * 32];
  __shared__ __align__(16) u16 sB[128 * 32];
  const int tid = threadIdx.x;
  const int wave = tid >> 6, lane = tid & 63;
  const int wr = wave >> 1, wc = wave & 1;
  const int lhi = lane >> 4, llo = lane & 15;
  const int m0 = blockIdx.y * 128;
  const int n0 = blockIdx.x * 128;

  const int c0i = tid, c1i = 256 + tid;          // 16B staging chunks
  const int ar0 = c0i >> 2, ac0 = (c0i & 3) * 8;
  const int ar1 = c1i >> 2, ac1 = (c1i & 3) * 8;
  u16* lA0 = sA + c0i * 8; u16* lA1 = sA + c1i * 8;
  u16* lB0 = sB + c0i * 8; u16* lB1 = sB + c1i * 8;

  floatx4 acc[4][4];
#pragma unroll
  for (int i = 0; i < 4; ++i)
#pragma unroll
    for (int j = 0; j < 4; ++j) acc[i][j] = floatx4{0.f, 0.f, 0.f, 0.f};

  for (int t = 0; t < nblk; ++t) {
    const int bld = ga.bld[t];
    const u16* ab = ga.a[t] + (size_t)(m0base + m0) * 512;
    const u16* bb = ga.b[t] + (size_t)n0 * bld + ga.bcol[t];
    const u16* pa0 = ab + (size_t)ar0 * 512 + ac0;
    const u16* pa1 = ab + (size_t)ar1 * 512 + ac1;
    const u16* pb0 = bb + (size_t)ar0 * bld + ac0;
    const u16* pb1 = bb + (size_t)ar1 * bld + ac1;
#pragma unroll 1
    for (int kk = 0; kk < 16; ++kk) {
      const int kl = kk * 32;
      __syncthreads();                           // prior iter's LDS reads done
      gl_lds16(pa0 + kl, lA0);
      gl_lds16(pa1 + kl, lA1);
      gl_lds16(pb0 + kl, lB0);
      gl_lds16(pb1 + kl, lB1);
      __syncthreads();                           // drain global_load_lds
      short8 af[4], bf[4];
#pragma unroll
      for (int i = 0; i < 4; ++i) {
        af[i] = *(const short8*)(sA + (wr * 64 + i * 16 + llo) * 32 + lhi * 8);
        bf[i] = *(const short8*)(sB + (wc * 64 + i * 16 + llo) * 32 + lhi * 8);
      }
#pragma unroll
      for (int i = 0; i < 4; ++i)
#pragma unroll
        for (int j = 0; j < 4; ++j)
          acc[i][j] = __builtin_amdgcn_mfma_f32_16x16x32_bf16(af[i], bf[j], acc[i][j], 0, 0, 0);
    }
  }

  const int rb = m0 + wr * 64 + lhi * 4;
  const int cb = n0 + wc * 64 + llo;
#pragma unroll
  for (int i = 0; i < 4; ++i)
#pragma unroll
    for (int j = 0; j < 4; ++j)
#pragma unroll
      for (int r = 0; r < 4; ++r)
        C[(size_t)(rb + i * 16 + r) * ldc + (cb + j * 16)] = acc[i][j][r];
}

// ========== 256x256 2-phase counted-vmcnt bf16 GEMM on COMPACTED live rows ==========
// bf16 C output. K-loop/schedule unchanged (round-5 verified ledger;
// SQ_LDS_BANK_CONFLICT = 0). ROUND-10 FIX: tile enumeration is COLUMN-major
// (m0 = sid % gridDim.y). Round-9's row-major + m204 XCD-swizzle gave XCDs 6-7
// exclusively dead tiles (live work on 5.5 XCDs -> 4 rounds, 260us). Column-major
// spreads dead m-tiles uniformly across each XCD's contiguous sid chunk.

#define SWZ(b) ((b) ^ ((((b) >> 7) & 7) << 4))

#define STAGE_A(KT, H, DB) do {                                               \
    const int t_ = (KT) >> 3;                                                 \
    const u16* ab_ = (t_ == 3) ? seqsb : (hpad + ((size_t)t_ << 14));         \
    const int ko_ = ((KT) & 7) << 6;                                          \
    gl_lds16(ab_ + (size_t)((H) ? aR10 : aR00) + ko_,                         \
             sm + (DB) * 32768 + (H) * 8192 + tid * 8);                       \
    gl_lds16(ab_ + (size_t)((H) ? aR11 : aR01) + ko_,                         \
             sm + (DB) * 32768 + (H) * 8192 + 4096 + tid * 8);                \
  } while (0)

#define STAGE_B(KT, H, DB) do {                                               \
    gl_lds16(Bcat + (size_t)(n0 + (H) * 128 + lr0) * 2048 + (KT) * 64 + le0,  \
             sm + (DB) * 32768 + 16384 + (H) * 8192 + tid * 8);               \
    gl_lds16(Bcat + (size_t)(n0 + (H) * 128 + lr1) * 2048 + (KT) * 64 + le1,  \
             sm + (DB) * 32768 + 16384 + (H) * 8192 + 4096 + tid * 8);        \
  } while (0)

#define READ_A(DST, MB)                                                       \
  _Pragma("unroll") for (int fi = 0; fi < 4; ++fi)                            \
  _Pragma("unroll") for (int ks = 0; ks < 2; ++ks)                            \
      DST[fi][ks] = *(const short8*)(sm + curo + (MB) * 8192 + aoff[fi][ks])

#define READ_B(DST, NB)                                                       \
  _Pragma("unroll") for (int fj = 0; fj < 2; ++fj)                            \
  _Pragma("unroll") for (int ks = 0; ks < 2; ++ks)                            \
      DST[fj][ks] = *(const short8*)(sm + curo + 16384 + (NB) * 8192 + boff[fj][ks])

#define MFMA_CLUSTER(MB, NB, AF, BF)                                          \
  __builtin_amdgcn_s_setprio(1);                                              \
  _Pragma("unroll") for (int fi = 0; fi < 4; ++fi)                            \
  _Pragma("unroll") for (int fj = 0; fj < 2; ++fj)                            \
  _Pragma("unroll") for (int ks = 0; ks < 2; ++ks)                            \
      acc[MB][NB][fi][fj] = __builtin_amdgcn_mfma_f32_16x16x32_bf16(          \
          AF[fi][ks], BF[fj][ks], acc[MB][NB][fi][fj], 0, 0, 0);              \
  __builtin_amdgcn_s_setprio(0)

__global__ __launch_bounds__(512, 2)
void gemm8_kernel(const u16* __restrict__ hpad, const u16* __restrict__ seqsb,
                  const u16* __restrict__ Bcat, const int* __restrict__ rowmap,
                  const int* __restrict__ meta, u16* __restrict__ C,
                  int m0base, int nkt) {
  __shared__ __align__(16) u16 sm[65536];        // 128 KiB
  const int tid = threadIdx.x;
  const int wave = tid >> 6, lane = tid & 63;
  const int llo = lane & 15, lhi = lane >> 4;
  const int wr = wave >> 2, wc = wave & 3;

  // XCD-aware bijective block-id swizzle (m204) + COLUMN-major tile mapping
  const int nwg = gridDim.x * gridDim.y;
  const int lin = blockIdx.y * gridDim.x + blockIdx.x;
  const int xcd = lin & 7, idx = lin >> 3;
  const int q = nwg >> 3, r = nwg & 7;
  const int sid = (xcd < r ? xcd * (q + 1) : r * (q + 1) + (xcd - r) * q) + idx;
  const int ny = gridDim.y;                      // # m-tiles
  const int m0 = (sid % ny) * 256;
  const int n0 = (sid / ny) * 256;

  const int live = meta[0];
  if (m0base + m0 >= live) return;               // dead tile (uniform) -> exit

  // staging source coords: linear LDS dest chunk i*16B holds logical byte SWZ(i*16)
  const int p0 = tid * 16, p1 = (512 + tid) * 16;
  const int q0 = SWZ(p0), q1 = SWZ(p1);
  const int lr0 = q0 >> 7, le0 = (q0 & 127) >> 1;
  const int lr1 = q1 >> 7, le1 = (q1 & 127) >> 1;

  // gather: per-thread original-row element offsets (fixed across the K-loop)
  const int aR00 = rowmap[m0base + m0 + lr0] * 512 + le0;
  const int aR01 = rowmap[m0base + m0 + lr1] * 512 + le1;
  const int aR10 = rowmap[m0base + m0 + 128 + lr0] * 512 + le0;
  const int aR11 = rowmap[m0base + m0 + 128 + lr1] * 512 + le1;

  // swizzled fragment read offsets (u16 units), half-relative
  int aoff[4][2], boff[2][2];
#pragma unroll
  for (int fi = 0; fi < 4; ++fi)
#pragma unroll
    for (int ks = 0; ks < 2; ++ks) {
      int by = (wr * 64 + fi * 16 + llo) * 128 + ks * 64 + lhi * 16;
      aoff[fi][ks] = SWZ(by) >> 1;
    }
#pragma unroll
  for (int fj = 0; fj < 2; ++fj)
#pragma unroll
    for (int ks = 0; ks < 2; ++ks) {
      int by = (wc * 32 + fj * 16 + llo) * 128 + ks * 64 + lhi * 16;
      boff[fj][ks] = SWZ(by) >> 1;
    }

  floatx4 acc[2][2][4][2];
#pragma unroll
  for (int mb = 0; mb < 2; ++mb)
#pragma unroll
    for (int nb = 0; nb < 2; ++nb)
#pragma unroll
      for (int fi = 0; fi < 4; ++fi)
#pragma unroll
        for (int fj = 0; fj < 2; ++fj)
          acc[mb][nb][fi][fj] = floatx4{0.f, 0.f, 0.f, 0.f};

  // prologue: kt0 fully + kt1.{A0,B0}; vmcnt(4) -> kt0 landed, 4 ops in flight
  STAGE_A(0, 0, 0); STAGE_B(0, 0, 0); STAGE_B(0, 1, 0); STAGE_A(0, 1, 0);
  STAGE_A(1, 0, 1); STAGE_B(1, 0, 1);
  asm volatile("s_waitcnt vmcnt(4)" ::: "memory");
  __builtin_amdgcn_s_barrier();

  short8 af[4][2], b0f[2][2], b1f[2][2];
  for (int j = 0; j < nkt; ++j) {
    const int cur = j & 1, nxt = cur ^ 1;
    const int curo = cur * 32768;
    // ---------------- phase A ----------------
    READ_A(af, 0);
    READ_B(b0f, 0);
    __builtin_amdgcn_sched_barrier(0);           // pin: b1f's 4 reads issue last
    READ_B(b1f, 1);
    if (j + 1 < nkt) {                           // stage kt j+1 -> nxt
      STAGE_B(j + 1, 1, nxt);
      STAGE_A(j + 1, 1, nxt);
    }
    __builtin_amdgcn_s_barrier();
    asm volatile("s_waitcnt lgkmcnt(4)" ::: "memory");   // A0+B0 done (DS in-order)
    __builtin_amdgcn_sched_barrier(0);
    MFMA_CLUSTER(0, 0, af, b0f);
    asm volatile("s_waitcnt lgkmcnt(0)" ::: "memory");   // B1 done
    __builtin_amdgcn_sched_barrier(0);
    MFMA_CLUSTER(0, 1, af, b1f);
    __builtin_amdgcn_s_barrier();
    // ---------------- phase B ----------------
    READ_A(af, 1);
    if (j + 2 < nkt) {                           // stage kt j+2 -> cur
      STAGE_A(j + 2, 0, cur);
      STAGE_B(j + 2, 0, cur);
    }
    __builtin_amdgcn_s_barrier();
    asm volatile("s_waitcnt lgkmcnt(0)" ::: "memory");
    __builtin_amdgcn_sched_barrier(0);
    MFMA_CLUSTER(1, 0, af, b0f);
    MFMA_CLUSTER(1, 1, af, b1f);
    if (j < nkt - 2) asm volatile("s_waitcnt vmcnt(4)" ::: "memory");
    else             asm volatile("s_waitcnt vmcnt(0)" ::: "memory");
    __builtin_amdgcn_s_barrier();
  }

#pragma unroll
  for (int mb = 0; mb < 2; ++mb)
#pragma unroll
    for (int nb = 0; nb < 2; ++nb)
#pragma unroll
      for (int fi = 0; fi < 4; ++fi)
#pragma unroll
        for (int fj = 0; fj < 2; ++fj)
#pragma unroll
          for (int rr = 0; rr < 4; ++rr)
            C[(size_t)(m0 + mb * 128 + wr * 64 + fi * 16 + lhi * 4 + rr) * N_TOT
              + (n0 + nb * 128 + wc * 32 + fj * 16 + llo)] = f2b(acc[mb][nb][fi][fj][rr]);
}

// ---- fi softmax-weighted reduction over s (chunked partials + atomics) ----
__global__ void k_fireduce(const float* __restrict__ Cfi, const float* __restrict__ a1v,
                           const float* __restrict__ c0, const int* __restrict__ seq_lens,
                           float* __restrict__ denom, float* __restrict__ cacc,
                           int sbase, int send) {
  int id = blockIdx.x * 256 + threadIdx.x;       // b*512+h
  int b = id >> 9, h = id & 511;
  int len = seq_lens[b * sl_stride(seq_lens)];
  int lim = (send < len) ? send : len;
  int s0 = sbase + blockIdx.y * 64;
  if (s0 >= lim) return;
  int s1 = (s0 + 64 < lim) ? s0 + 64 : lim;
  float a = a1v[id];
  float d = 0.f, ca = 0.f;
  for (int s = s0; s < s1; ++s) {
    size_t m = (size_t)(s * 32 + b);
    size_t ml = (size_t)((s - sbase) * 32 + b);
    float e = __expf(sigm(Cfi[ml * 512 + h] + a));
    d += e;
    ca += e * c0[m * 512 + h];
  }
  atomicAdd(&denom[id], d);
  atomicAdd(&cacc[id], ca);
}

// ---- global cell: c_g, h_g → out row S ----
__global__ void k_global(const float* __restrict__ sg0, const float* __restrict__ sg2,
                         const float* __restrict__ c0, const float* __restrict__ denom,
                         const float* __restrict__ cacc, float* __restrict__ out) {
  int id = blockIdx.x * 256 + threadIdx.x;       // 16384
  float fg = sigm(sg0[id]);
  float og = sigm(sg2[id]);
  float cg1 = c0[(size_t)HG_ROW + id];
  float dn = denom[id];
  float cg = fg * cg1 + cacc[id] / (dn > 0.f ? dn : 1.f);
  float hg = og * tanh_(cg);
  out[(size_t)HG_ROW + id] = hg;
  out[(size_t)CT_BASE + HG_ROW + id] = cg;
}

// ---- window epilogue on compact rows: gates softmax-5, c_w, h_w; scatter via rowmap ----
__global__ void k_epilogue(const u16* __restrict__ Cch, const float* __restrict__ Vb,
                           const float* __restrict__ c0, const int* __restrict__ seq_lens,
                           const int* __restrict__ rowmap, const int* __restrict__ meta,
                           float* __restrict__ out, int mbase) {
  int idx = blockIdx.x * 256 + threadIdx.x;      // chunk-local (compact ml, h)
  int ml = idx >> 9, h = idx & 511;
  int cml = mbase + ml;
  if (cml >= meta[0]) return;                    // past live rows (block-uniform)
  int mg = rowmap[cml];
  int s = mg >> 5, b = mg & 31;
  int len = seq_lens[b * sl_stride(seq_lens)];
  float pre[7];
#pragma unroll
  for (int g = 0; g < 7; ++g)
    pre[g] = b2f(Cch[(size_t)ml * N_TOT + g * 512 + h]) + Vb[(size_t)(g * 32 + b) * 512 + h];
  float i_ = sigm(pre[0]);
  float l_ = sigm(pre[1]);
  float r_ = sigm(pre[2]);
  float f_ = sigm(pre[3]);
  float sg = sigm(pre[4]);
  float o_ = sigm(pre[5]);
  float u_ = tanh_(pre[6]);
  float el = __expf(l_), ef = __expf(f_), er = __expf(r_), es = __expf(sg), ei = __expf(i_);
  float inv = 1.f / (el + ef + er + es + ei);
  float cw = 0.f;
  if (s < len) {                                 // always true for live rows
    float cl = (s >= 1) ? c0[(size_t)(mg - 32) * 512 + h] : 0.f;
    float cc = c0[(size_t)mg * 512 + h];
    float cr = (s + 1 < S_LEN && s + 1 < len) ? c0[(size_t)(mg + 32) * 512 + h] : 0.f;
    float cg1 = c0[(size_t)HG_ROW + b * 512 + h];
    cw = (el * cl + ef * cc + er * cr + es * cg1 + ei * u_) * inv;
  }
  float hw = o_ * tanh_(cw);
  size_t oi = (size_t)mg * 512 + h;
  out[oi] = hw;
  out[(size_t)CT_BASE + oi] = cw;
}

extern "C" void kernel_launch(void* const* d_in, const int* in_sizes, int n_in,
                              void* d_out, int out_size, void* d_ws, size_t ws_size,
                              hipStream_t stream) {
  const float* seqs = (const float*)d_in[0];
  const int* seq_lens = (const int*)d_in[1];
  const float* h0 = (const float*)d_in[2];
  const float* c0 = (const float*)d_in[3];
  const float* Ww = (const float*)d_in[4];
  const float* Wu = (const float*)d_in[5];
  const float* Wv = (const float*)d_in[6];
  const float* Wb = (const float*)d_in[7];
  const float* Sw = (const float*)d_in[8];
  const float* Su = (const float*)d_in[9];
  const float* Sb = (const float*)d_in[10];
  float* out = (float*)d_out;

  // ---- workspace layout (fixed ~63 MB) + adaptive C region ----
  char* ws = (char*)d_ws;
  size_t off = 0;
  float* denom = (float*)(ws + off); off += 16384 * 4;   // zeroed together:
  float* cacc  = (float*)(ws + off); off += 16384 * 4;   // denom, cacc, hhat
  float* hhat  = (float*)(ws + off); off += 16384 * 4;
  float* sg0  = (float*)(ws + off); off += 16384 * 4;
  float* sg2  = (float*)(ws + off); off += 16384 * 4;
  float* a1v  = (float*)(ws + off); off += 16384 * 4;
  float* Vb   = (float*)(ws + off); off += (size_t)7 * 16384 * 4;
  u16* hpad  = (u16*)(ws + off); off += (size_t)16448 * 512 * 2;   // 16.84 MB
  u16* seqsb = (u16*)(ws + off); off += (size_t)16384 * 512 * 2;   // 16.78 MB
  u16* Bcat  = (u16*)(ws + off); off += (size_t)3584 * 2048 * 2;   // 14.68 MB
  u16* Bfi   = (u16*)(ws + off); off += (size_t)512 * 512 * 2;     //  0.52 MB
  u16* Ball  = (u16*)(ws + off); off += (size_t)5120 * 1024 * 2;   // 10.49 MB
  u16* Ahg   = (u16*)(ws + off); off += (size_t)128 * 512 * 2;
  u16* Ahh   = (u16*)(ws + off); off += (size_t)128 * 512 * 2;
  float* Csm = (float*)(ws + off); off += (size_t)128 * 5120 * 4;  //  2.62 MB
  int* meta   = (int*)(ws + off); off += 64 * 4;                   // live + prefix
  int* rowmap = (int*)(ws + off); off += 16640 * 4;                // live-row gather map
  float* Cfi  = (float*)(ws + off);              // fi GEMM C (f32), aliases Cb16
  u16* Cb16   = (u16*)(ws + off);                // main GEMM C (bf16), sequential use

  size_t avail = (ws_size > off) ? (ws_size - off) : 0;

  // fused prep (incl. Ball/Ahg/Ahh for the small GEMM)
  k_prep<<<18897, 256, 0, stream>>>(h0, seq_lens, seqs, Ww, Wu, Su, Sw, Wv,
                                    hpad, seqsb, Bcat, Bfi, denom, rowmap,
                                    Ball, Ahg, Ahh, out);
  k_map0<<<1, 64, 0, stream>>>(seq_lens, meta);
  k_mapfill<<<64, 256, 0, stream>>>(seq_lens, meta, rowmap);
  k_hhat<<<dim3(64, 16), 256, 0, stream>>>(hpad, hhat);
  k_cvthh<<<8, 256, 0, stream>>>(hhat, Ahh);

  // small matmuls as ONE GEMM: C[32x5120] = [h_g1|hhat] @ [W_all|Su_or_0]^T
  GemmSrc gsm;
  gsm.a[0] = Ahg; gsm.b[0] = Ball; gsm.bld[0] = 1024; gsm.bcol[0] = 0;
  gsm.a[1] = Ahh; gsm.b[1] = Ball; gsm.bld[1] = 1024; gsm.bcol[1] = 512;
  gemm_kernel<<<dim3(40, 1), 256, 0, stream>>>(gsm, Csm, 5120, 2, 0);
  k_scatter<<<640, 256, 0, stream>>>(Csm, Sb, Wb, sg0, sg2, a1v, Vb);

  // fi GEMM (16384 x 512) = h_w1 @ Su[1]^T, chunked over rows (f32 C)
  int fi_rows = (int)(avail / ((size_t)512 * 4));
  fi_rows = (fi_rows / 128) * 128;
  if (fi_rows > 16384) fi_rows = 16384;
  if (fi_rows < 128) fi_rows = 128;
  GemmSrc gfi;
  gfi.a[0] = hpad + 32 * 512; gfi.b[0] = Bfi; gfi.bld[0] = 512; gfi.bcol[0] = 0;
  for (int fb = 0; fb < 16384; fb += fi_rows) {
    int rows = (fi_rows < 16384 - fb) ? fi_rows : (16384 - fb);
    gemm_kernel<<<dim3(4, rows / 128), 256, 0, stream>>>(gfi, Cfi, 512, 1, fb);
    int sbase = fb / 32, scnt = rows / 32;
    k_fireduce<<<dim3(64, (scnt + 63) / 64), 256, 0, stream>>>(
        Cfi, a1v, c0, seq_lens, denom, cacc, sbase, sbase + scnt);
  }
  k_global<<<64, 256, 0, stream>>>(sg0, sg2, c0, denom, cacc, out);

  // main GEMM on compacted live rows (bf16 C).
  const size_t full_bytes = (size_t)16384 * N_TOT * 2;
  if (avail >= full_bytes) {
    gemm8_kernel<<<dim3(14, 64), 512, 0, stream>>>(
        hpad, seqsb, Bcat, rowmap, meta, Cb16, 0, 32);
    k_epilogue<<<32768, 256, 0, stream>>>(Cb16, Vb, c0, seq_lens, rowmap, meta, out, 0);
  } else {
    int chunk_rows = (int)(avail / ((size_t)N_TOT * 2));
    chunk_rows = (chunk_rows / 256) * 256;
    if (chunk_rows > 8192) chunk_rows = 8192;
    if (chunk_rows < 256) chunk_rows = 256;
    for (int mb = 0; mb < 16384; mb += chunk_rows) {
      int rows = (chunk_rows < 16384 - mb) ? chunk_rows : (16384 - mb);
      gemm8_kernel<<<dim3(14, rows / 256), 512, 0, stream>>>(
          hpad, seqsb, Bcat, rowmap, meta, Cb16, mb, 32);
      k_epilogue<<<rows * 2, 256, 0, stream>>>(Cb16, Vb, c0, seq_lens, rowmap, meta, out, mb);
    }
  }
}